// Round 1
// baseline (606.455 us; speedup 1.0000x reference)
//
#include <hip/hip_runtime.h>
#include <hip/hip_bf16.h>

#define NUM_USERS 100000
#define NUM_ITEMS 50000
#define EMBED     64
#define S_NNZ     (NUM_USERS * 32)
#define R_NNZ     (NUM_USERS * 50)
#define BATCH     8192

// bucket sort parameters: 256 buckets x 391 rows, 256 chunks x 12500 edges
#define NB    256
#define NCH   256
#define CHUNK (S_NNZ / NCH)      // 12500
#define BROWS 391                // 391*256 = 100096 >= NUM_USERS

// ---------------- two-pass bucket CSR build ----------------

// pass 1a: per-chunk bucket histogram -> cnt_t[bucket*NCH + chunk]
__global__ __launch_bounds__(256) void k_p1hist(const int* __restrict__ rows, int* __restrict__ cnt_t) {
    __shared__ int h[NB];
    int t = threadIdx.x, b = blockIdx.x;
    h[t] = 0;
    __syncthreads();
    int base = b * CHUNK;
    for (int i = t; i < CHUNK; i += 256) atomicAdd(&h[rows[base + i] / BROWS], 1);
    __syncthreads();
    cnt_t[t * NCH + b] = h[t];
}

// flat exclusive scan over 65536 ints
__global__ __launch_bounds__(1024) void k_scan1(const int* __restrict__ cnt, int* __restrict__ excl,
                                                int* __restrict__ bsums, int n) {
    __shared__ int buf[1024];
    int t = threadIdx.x;
    int i = blockIdx.x * 1024 + t;
    int x = (i < n) ? cnt[i] : 0;
    buf[t] = x;
    __syncthreads();
    for (int off = 1; off < 1024; off <<= 1) {
        int y = (t >= off) ? buf[t - off] : 0;
        __syncthreads();
        buf[t] += y;
        __syncthreads();
    }
    if (i < n) excl[i] = buf[t] - x;
    if (t == 1023) bsums[blockIdx.x] = buf[1023];
}

__global__ __launch_bounds__(1024) void k_scan2(int* __restrict__ bsums, int nb, int* __restrict__ total_slot) {
    __shared__ int buf[1024];
    int t = threadIdx.x;
    int x = (t < nb) ? bsums[t] : 0;
    buf[t] = x;
    __syncthreads();
    for (int off = 1; off < 1024; off <<= 1) {
        int y = (t >= off) ? buf[t - off] : 0;
        __syncthreads();
        buf[t] += y;
        __syncthreads();
    }
    if (t < nb) bsums[t] = buf[t] - x;
    if (t == 1023) total_slot[0] = buf[1023];
}

__global__ void k_scan3b(int* __restrict__ a, const int* __restrict__ bsums, int n) {
    int i = blockIdx.x * blockDim.x + threadIdx.x;
    if (i < n) a[i] += bsums[i >> 10];
}

// pass 1b: write chunk's edges into per-(chunk,bucket) contiguous runs.
// packed: x = (rowloc<<17)|col (rowloc<391 fits 9b, col<2^17), y = val bits
__global__ __launch_bounds__(256) void k_p1scatter(const int* __restrict__ rows, const int* __restrict__ cols,
                                                   const float* __restrict__ vals, const int* __restrict__ cnt_t,
                                                   int2* __restrict__ tmpE) {
    __shared__ int cur[NB];
    int t = threadIdx.x, b = blockIdx.x;
    cur[t] = cnt_t[t * NCH + b];
    __syncthreads();
    int base = b * CHUNK;
    for (int i = t; i < CHUNK; i += 256) {
        int e  = base + i;
        int r  = rows[e];
        int bk = r / BROWS;
        int pos = atomicAdd(&cur[bk], 1);
        tmpE[pos] = make_int2(((r - bk * BROWS) << 17) | cols[e], __float_as_int(vals[e]));
    }
}

// pass 2: exact CSR within each bucket (100 KB window, one block) + rowptr
__global__ __launch_bounds__(512) void k_p2(const int2* __restrict__ tmpE, const int* __restrict__ cnt_t,
                                            int* __restrict__ rowptr, int2* __restrict__ colval) {
    __shared__ int h[512];
    __shared__ int s[512];
    __shared__ int cur[512];
    int t = threadIdx.x, k = blockIdx.x;
    int beg = cnt_t[k * NCH];
    int end = (k < NB - 1) ? cnt_t[(k + 1) * NCH] : S_NNZ;
    h[t] = 0;
    __syncthreads();
    for (int j = beg + t; j < end; j += 512) atomicAdd(&h[((unsigned)tmpE[j].x) >> 17], 1);
    __syncthreads();
    s[t] = h[t];
    __syncthreads();
    for (int off = 1; off < 512; off <<= 1) {
        int y = (t >= off) ? s[t - off] : 0;
        __syncthreads();
        s[t] += y;
        __syncthreads();
    }
    int excl = s[t] - h[t];
    int gr   = k * BROWS + t;
    if (t <= BROWS && gr <= NUM_USERS) rowptr[gr] = beg + excl;
    cur[t] = beg + excl;
    __syncthreads();
    for (int j = beg + t; j < end; j += 512) {
        int2 e  = tmpE[j];
        int pos = atomicAdd(&cur[((unsigned)e.x) >> 17], 1);
        colval[pos] = make_int2(e.x & 0x1FFFF, e.y);
    }
}

// ---------------- converts ----------------
__global__ void k_cvt(const float* __restrict__ src, __hip_bfloat16* __restrict__ dst, int n) {
    int i = blockIdx.x * blockDim.x + threadIdx.x;
    if (i < n) dst[i] = __float2bfloat16(src[i]);
}

// ---------------- SpMM (CSR gather, bf16 table, unroll x8) ----------------
__global__ __launch_bounds__(256) void k_spmm16(const int* __restrict__ rowptr,
                                                const int2* __restrict__ colval,
                                                const __hip_bfloat16* __restrict__ X,
                                                float* __restrict__ Y, int n_rows) {
    int w    = blockIdx.x * (blockDim.x >> 6) + (threadIdx.x >> 6);
    int lane = threadIdx.x & 63;
    if (w >= n_rows) return;
    int beg = rowptr[w], end = rowptr[w + 1];
    float acc = 0.0f;
    int j    = beg;
    int jend = beg + ((end - beg) & ~7);
    for (; j < jend; j += 8) {
        int2 cv[8];
#pragma unroll
        for (int u = 0; u < 8; ++u) cv[u] = colval[j + u];
        float x[8];
#pragma unroll
        for (int u = 0; u < 8; ++u) x[u] = __bfloat162float(X[(size_t)cv[u].x * EMBED + lane]);
#pragma unroll
        for (int u = 0; u < 8; ++u) acc = fmaf(__int_as_float(cv[u].y), x[u], acc);
    }
    for (; j < end; ++j)
        acc = fmaf(__int_as_float(colval[j].y), __bfloat162float(X[(size_t)colval[j].x * EMBED + lane]), acc);
    Y[(size_t)w * EMBED + lane] = acc;
}

__global__ __launch_bounds__(256) void k_spmm_batch16(const int* __restrict__ rowptr,
                                                      const int2* __restrict__ colval,
                                                      const __hip_bfloat16* __restrict__ X,
                                                      const int* __restrict__ bu,
                                                      float* __restrict__ Agg2, int n) {
    int w    = blockIdx.x * (blockDim.x >> 6) + (threadIdx.x >> 6);
    int lane = threadIdx.x & 63;
    if (w >= n) return;
    int r   = bu[w];
    int beg = rowptr[r], end = rowptr[r + 1];
    float acc = 0.0f;
    int j    = beg;
    int jend = beg + ((end - beg) & ~7);
    for (; j < jend; j += 8) {
        int2 cv[8];
#pragma unroll
        for (int u = 0; u < 8; ++u) cv[u] = colval[j + u];
        float x[8];
#pragma unroll
        for (int u = 0; u < 8; ++u) x[u] = __bfloat162float(X[(size_t)cv[u].x * EMBED + lane]);
#pragma unroll
        for (int u = 0; u < 8; ++u) acc = fmaf(__int_as_float(cv[u].y), x[u], acc);
    }
    for (; j < end; ++j)
        acc = fmaf(__int_as_float(colval[j].y), __bfloat162float(X[(size_t)colval[j].x * EMBED + lane]), acc);
    Agg2[(size_t)w * EMBED + lane] = acc;
}

// ---------------- dense layers ----------------
// layer0: writes fp32 Uout AND bf16 Uout16 (gather table for SpMM2)
__global__ __launch_bounds__(256) void k_layer(const float* __restrict__ Agg,
                                               const float* __restrict__ Uin,
                                               float* __restrict__ Uout,
                                               __hip_bfloat16* __restrict__ Uout16,
                                               const float* __restrict__ W,
                                               const float* __restrict__ b) {
    __shared__ float Wl[128 * 64];
    __shared__ float xs[16][128];
    int t = threadIdx.x;
    for (int i = t; i < 128 * 64; i += 256) Wl[i] = W[i];
    int rl = t >> 6;
    int c  = t & 63;
    int rbase = blockIdx.x * 16;
#pragma unroll
    for (int q = 0; q < 4; ++q) {
        int rr = rbase + rl * 4 + q;
        if (rr < NUM_USERS) {
            xs[rl * 4 + q][c]      = Agg[(size_t)rr * EMBED + c];
            xs[rl * 4 + q][64 + c] = Uin[(size_t)rr * EMBED + c];
        }
    }
    __syncthreads();
    float bias = b[c];
#pragma unroll
    for (int q = 0; q < 4; ++q) {
        int rr = rbase + rl * 4 + q;
        if (rr >= NUM_USERS) break;
        float acc = bias;
#pragma unroll
        for (int k = 0; k < 128; ++k) acc = fmaf(xs[rl * 4 + q][k], Wl[k * 64 + c], acc);
        float v = fmaxf(acc, 0.0f);
        Uout[(size_t)rr * EMBED + c]   = v;
        Uout16[(size_t)rr * EMBED + c] = __float2bfloat16(v);
    }
}

__global__ __launch_bounds__(256) void k_layer_batch(const float* __restrict__ Agg2,
                                                     const float* __restrict__ Uin,
                                                     const int* __restrict__ bu,
                                                     float* __restrict__ out0,
                                                     const float* __restrict__ W,
                                                     const float* __restrict__ b) {
    __shared__ float Wl[128 * 64];
    __shared__ float xs[16][128];
    int t = threadIdx.x;
    for (int i = t; i < 128 * 64; i += 256) Wl[i] = W[i];
    int rl = t >> 6;
    int c  = t & 63;
    int rbase = blockIdx.x * 16;
#pragma unroll
    for (int q = 0; q < 4; ++q) {
        int s = rbase + rl * 4 + q;
        if (s < BATCH) {
            xs[rl * 4 + q][c]      = Agg2[(size_t)s * EMBED + c];
            xs[rl * 4 + q][64 + c] = Uin[(size_t)bu[s] * EMBED + c];
        }
    }
    __syncthreads();
    float bias = b[c];
#pragma unroll
    for (int q = 0; q < 4; ++q) {
        int s = rbase + rl * 4 + q;
        if (s >= BATCH) break;
        float acc = bias;
#pragma unroll
        for (int k = 0; k < 128; ++k) acc = fmaf(xs[rl * 4 + q][k], Wl[k * 64 + c], acc);
        out0[(size_t)s * EMBED + c] = fmaxf(acc, 0.0f);
    }
}

// ---------------- R handling: batch-restricted CSR + register-accum SpMM ----------------

__global__ void k_chain(const int* __restrict__ bu, int* __restrict__ head,
                        int* __restrict__ nxt, int n) {
    int i = blockIdx.x * blockDim.x + threadIdx.x;
    if (i < n) nxt[i] = atomicExch(&head[bu[i]], i);
}

// pass 1: histogram of matched edges per chain-head batch slot
__global__ __launch_bounds__(256) void k_rcount(const int* __restrict__ rows,
                                                const int* __restrict__ head,
                                                int* __restrict__ cnt, int nnz) {
    int e = blockIdx.x * blockDim.x + threadIdx.x;
    if (e >= nnz) return;
    int h = head[rows[e]];
    if (h >= 0) atomicAdd(&cnt[h], 1);
}

// exclusive scan over 8192 counts (one block), writes rowptr2[8193] and cursor copy
__global__ __launch_bounds__(1024) void k_rscan(const int* __restrict__ cnt,
                                                int* __restrict__ rowptr2,
                                                int* __restrict__ cur) {
    __shared__ int buf[1024];
    int t = threadIdx.x;
    int loc[8];
    int sum = 0;
#pragma unroll
    for (int q = 0; q < 8; ++q) { loc[q] = cnt[t * 8 + q]; sum += loc[q]; }
    buf[t] = sum;
    __syncthreads();
    for (int off = 1; off < 1024; off <<= 1) {
        int y = (t >= off) ? buf[t - off] : 0;
        __syncthreads();
        buf[t] += y;
        __syncthreads();
    }
    int excl = buf[t] - sum;
#pragma unroll
    for (int q = 0; q < 8; ++q) {
        rowptr2[t * 8 + q] = excl;
        cur[t * 8 + q]     = excl;
        excl += loc[q];
    }
    if (t == 1023) rowptr2[BATCH] = excl;
}

// pass 2: scatter matched (col,val) into per-slot CSR runs
__global__ __launch_bounds__(256) void k_rscatter(const int* __restrict__ rows,
                                                  const int* __restrict__ cols,
                                                  const float* __restrict__ vals,
                                                  const int* __restrict__ head,
                                                  int* __restrict__ cur,
                                                  int2* __restrict__ colval2, int nnz) {
    int e = blockIdx.x * blockDim.x + threadIdx.x;
    if (e >= nnz) return;
    int h = head[rows[e]];
    if (h < 0) return;
    int pos = atomicAdd(&cur[h], 1);
    colval2[pos] = make_int2(cols[e], __float_as_int(vals[e]));
}

// pass 3: per-chain-head gather SpMM, register accumulate, write once per slot along chain
__global__ __launch_bounds__(256) void k_rspmm(const int* __restrict__ rowptr2,
                                               const int2* __restrict__ colval2,
                                               const __hip_bfloat16* __restrict__ V16,
                                               const int* __restrict__ bu,
                                               const int* __restrict__ head,
                                               const int* __restrict__ nxt,
                                               float* __restrict__ out0) {
    int s    = blockIdx.x * (blockDim.x >> 6) + (threadIdx.x >> 6);
    int lane = threadIdx.x & 63;
    if (s >= BATCH) return;
    if (head[bu[s]] != s) return;       // only chain heads own edges
    int beg = rowptr2[s], end = rowptr2[s + 1];
    float acc = 0.0f;
    int j    = beg;
    int jend = beg + ((end - beg) & ~7);
    for (; j < jend; j += 8) {
        int2 cv[8];
#pragma unroll
        for (int u = 0; u < 8; ++u) cv[u] = colval2[j + u];
        float x[8];
#pragma unroll
        for (int u = 0; u < 8; ++u) x[u] = __bfloat162float(V16[(size_t)cv[u].x * EMBED + lane]);
#pragma unroll
        for (int u = 0; u < 8; ++u) acc = fmaf(__int_as_float(cv[u].y), x[u], acc);
    }
    for (; j < end; ++j)
        acc = fmaf(__int_as_float(colval2[j].y), __bfloat162float(V16[(size_t)colval2[j].x * EMBED + lane]), acc);
    // walk duplicate-user chain; each slot written exactly once across all waves
    int slot = s;
    while (slot >= 0) {
        out0[(size_t)slot * EMBED + lane] += acc;
        slot = nxt[slot];
    }
}

// ---------------- final gathers (bp/bn only, exact fp32 V) ----------------
__global__ void k_gather2(const float* __restrict__ V,
                          const int* __restrict__ bp, const int* __restrict__ bn,
                          float* __restrict__ out) {
    int i = blockIdx.x * blockDim.x + threadIdx.x;
    if (i >= BATCH * EMBED) return;
    int row = i >> 6, l = i & 63;
    out[BATCH * EMBED + i]     = V[(size_t)bp[row] * EMBED + l];
    out[2 * BATCH * EMBED + i] = V[(size_t)bn[row] * EMBED + l];
}

// ---------------- launch ----------------

extern "C" void kernel_launch(void* const* d_in, const int* in_sizes, int n_in,
                              void* d_out, int out_size, void* d_ws, size_t ws_size,
                              hipStream_t stream) {
    const int*   batch_user = (const int*)d_in[0];
    const int*   batch_pos  = (const int*)d_in[1];
    const int*   batch_neg  = (const int*)d_in[2];
    const float* U     = (const float*)d_in[3];
    const float* V     = (const float*)d_in[4];
    const float* W0    = (const float*)d_in[5];
    const float* b0    = (const float*)d_in[6];
    const float* W1    = (const float*)d_in[7];
    const float* b1    = (const float*)d_in[8];
    const int*   S_row = (const int*)d_in[9];
    const int*   S_col = (const int*)d_in[10];
    const float* S_val = (const float*)d_in[11];
    const int*   R_row = (const int*)d_in[12];
    const int*   R_col = (const int*)d_in[13];
    const float* R_val = (const float*)d_in[14];
    float* out = (float*)d_out;

    const size_t tabElems = (size_t)NUM_USERS * EMBED;   // 6.4M

    // workspace layout. tmpE aliases A (both 25.6 MB; tmpE dead before A written).
    // X16 region (12.8 MB) sequentially holds U16 -> A16 -> V16.
    // colval2 aliases A (A dead after k_layer_batch).
    char* wsb = (char*)d_ws;
    size_t o = 0;
    float* A       = (float*)(wsb + o); o += tabElems * 4;            // U1 fp32 (alias: tmpE, colval2)
    float* B       = (float*)(wsb + o); o += tabElems * 4;            // agg fp32
    float* Agg2    = (float*)(wsb + o); o += (size_t)BATCH * EMBED * 4;
    int*   rowptrS = (int*)(wsb + o);   o += (NUM_USERS + 1) * 4;
    int*   cnt_t   = (int*)(wsb + o);   o += (size_t)NB * NCH * 4;
    int*   bsums   = (int*)(wsb + o);   o += 1024 * 4;
    int*   head    = (int*)(wsb + o);   o += NUM_USERS * 4;
    int*   nxt     = (int*)(wsb + o);   o += BATCH * 4;
    int*   cntR    = (int*)(wsb + o);   o += BATCH * 4;
    int*   rowptr2 = (int*)(wsb + o);   o += (BATCH + 1) * 4;
    int*   curR    = (int*)(wsb + o);   o += BATCH * 4;
    o = (o + 7) & ~(size_t)7;
    int2*  colvalS = (int2*)(wsb + o);  o += (size_t)S_NNZ * 8;
    __hip_bfloat16* X16 = (__hip_bfloat16*)(wsb + o); o += tabElems * 2;

    int2* tmpE    = (int2*)A;
    int2* colval2 = (int2*)A;   // alias: A dead after k_layer_batch

    const int spmm_blocks  = (NUM_USERS * 64 + 255) / 256;
    const int layer_blocks = (NUM_USERS + 15) / 16;

    // ---- CSR of S: two-pass bucket sort ----
    k_p1hist<<<NCH, 256, 0, stream>>>(S_row, cnt_t);
    k_scan1<<<(NB * NCH) / 1024, 1024, 0, stream>>>(cnt_t, cnt_t, bsums, NB * NCH);
    k_scan2<<<1, 1024, 0, stream>>>(bsums, (NB * NCH) / 1024, &bsums[512]);
    k_scan3b<<<(NB * NCH) / 256, 256, 0, stream>>>(cnt_t, bsums, NB * NCH);
    k_p1scatter<<<NCH, 256, 0, stream>>>(S_row, S_col, S_val, cnt_t, tmpE);
    k_p2<<<NB, 512, 0, stream>>>(tmpE, cnt_t, rowptrS, colvalS);

    // ---- layer 0 (full): U16 table, SpMM1, layer (emits A + A16) ----
    k_cvt<<<(int)((tabElems + 255) / 256), 256, 0, stream>>>(U, X16, (int)tabElems);
    k_spmm16<<<spmm_blocks, 256, 0, stream>>>(rowptrS, colvalS, X16, B, NUM_USERS);
    k_layer<<<layer_blocks, 256, 0, stream>>>(B, U, A, X16, W0, b0);   // X16 now = A16

    // ---- chain map for R (user -> batch slots) ----
    hipMemsetAsync(head, 0xFF, NUM_USERS * sizeof(int), stream);
    k_chain<<<(BATCH + 255) / 256, 256, 0, stream>>>(batch_user, head, nxt, BATCH);

    // ---- layer 1 (batch-restricted), writes u2 into out0 ----
    k_spmm_batch16<<<(BATCH * 64 + 255) / 256, 256, 0, stream>>>(rowptrS, colvalS, X16, batch_user, Agg2, BATCH);
    k_layer_batch<<<(BATCH + 15) / 16, 256, 0, stream>>>(Agg2, A, batch_user, out, W1, b1);

    // ---- out0 += (R @ V)[batch rows]: batch-restricted CSR + register SpMM ----
    hipMemsetAsync(cntR, 0, BATCH * sizeof(int), stream);
    k_rcount<<<(R_NNZ + 255) / 256, 256, 0, stream>>>(R_row, head, cntR, R_NNZ);
    k_rscan<<<1, 1024, 0, stream>>>(cntR, rowptr2, curR);
    k_rscatter<<<(R_NNZ + 255) / 256, 256, 0, stream>>>(R_row, R_col, R_val, head, curR, colval2, R_NNZ);
    k_cvt<<<(int)(((size_t)NUM_ITEMS * EMBED + 255) / 256), 256, 0, stream>>>(V, X16, NUM_ITEMS * EMBED); // X16 now = V16
    k_rspmm<<<(BATCH * 64 + 255) / 256, 256, 0, stream>>>(rowptr2, colval2, X16, batch_user, head, nxt, out);

    // ---- bp/bn gathers (exact fp32 V) ----
    k_gather2<<<(BATCH * EMBED + 255) / 256, 256, 0, stream>>>(V, batch_pos, batch_neg, out);
}